// Round 3
// baseline (8080.132 us; speedup 1.0000x reference)
//
#include <hip/hip_runtime.h>

#define B_N 262144
#define T_STEPS 100
#define BETA_START 1e-4f
#define BETA_END 0.02f

typedef __bf16 bf16x8 __attribute__((ext_vector_type(8)));
typedef float f32x4 __attribute__((ext_vector_type(4)));

__device__ __forceinline__ float siluf(float z) {
  float e = __expf(-z);
  return z * __builtin_amdgcn_rcpf(1.0f + e);
}

__device__ __forceinline__ unsigned bbits(float f) {
  __bf16 h = (__bf16)f;
  return (unsigned)__builtin_bit_cast(unsigned short, h);
}
__device__ __forceinline__ unsigned pack2(float lo, float hi) {
  return bbits(lo) | (bbits(hi) << 16);
}
__device__ __forceinline__ float unlo(unsigned u) { return __uint_as_float(u << 16); }
__device__ __forceinline__ float unhi(unsigned u) { return __uint_as_float(u & 0xffff0000u); }

// Block: 256 threads = 4 waves; each wave owns 16 rows (ONE 16x16 MFMA tile).
// Grid: B_N/64 = 4096 blocks. Per-wave state halved vs round 2 (acc 32 AGPR,
// c1p 16 VGPR) so 2-3 waves/SIMD co-reside and the trans/VALU/LDS/MFMA pipes
// overlap across waves instead of serializing on one wave's issue stream.
// launch_bounds(256,2): cap total regs at 256 -> >=2 waves/SIMD guaranteed.
__global__ __launch_bounds__(256, 2) void diff_kernel(
    const float* __restrict__ ctx, const float* __restrict__ x_init,
    const float* __restrict__ noise, const float* __restrict__ W1,
    const float* __restrict__ b1, const float* __restrict__ W2,
    const float* __restrict__ b2, const float* __restrict__ W3,
    const float* __restrict__ b3, const float* __restrict__ temb,
    float* __restrict__ out) {
  __shared__ alignas(16) unsigned short sW[128][136];  // W^T, bf16 bits, padded
  __shared__ float sx[64];                             // per-row x broadcast
  __shared__ alignas(8) unsigned swxt[128];            // pack2(w1x[c], w1t[c])
  __shared__ float sb2[128];
  __shared__ float sw3[128];

  const int tid = threadIdx.x;
  const int lane = tid & 63;
  const int wv = tid >> 6;   // wave 0..3
  const int ar = lane & 15;  // A-frag row / C-frag col-low
  const int kg = lane >> 4;  // 0..3 k-group
  const int rowW = blockIdx.x * 64 + wv * 16;

  // ---- stage W1[:128]^T as bf16; small per-step constant tables ----
  for (int i = tid; i < 128 * 128; i += 256) {
    int k = i >> 7, n = i & 127;
    sW[n][k] = (unsigned short)bbits(W1[i]);
  }
  if (tid < 128) {
    swxt[tid] = pack2(W1[128 * 128 + tid], W1[129 * 128 + tid]);
    sb2[tid] = b2[tid];
    sw3[tid] = W3[tid];
  }
  __syncthreads();

  // ---- C1 = ctx @ W1[:128] + b1 (bf16 MFMA), one 16-row tile per wave ----
  f32x4 acc[8];
#pragma unroll
  for (int nt = 0; nt < 8; ++nt) {
    float b1c = b1[nt * 16 + ar];
    acc[nt] = (f32x4){b1c, b1c, b1c, b1c};
  }
  {
    const float4* crow4 = reinterpret_cast<const float4*>(ctx + (size_t)(rowW + ar) * 128);
    bf16x8 caf[4];
#pragma unroll
    for (int kk = 0; kk < 4; ++kk) {
      float4 a = crow4[kk * 8 + kg * 2];
      float4 b = crow4[kk * 8 + kg * 2 + 1];
      caf[kk][0] = (__bf16)a.x; caf[kk][1] = (__bf16)a.y;
      caf[kk][2] = (__bf16)a.z; caf[kk][3] = (__bf16)a.w;
      caf[kk][4] = (__bf16)b.x; caf[kk][5] = (__bf16)b.y;
      caf[kk][6] = (__bf16)b.z; caf[kk][7] = (__bf16)b.w;
    }
#pragma unroll
    for (int kk = 0; kk < 4; ++kk)
#pragma unroll
      for (int nt = 0; nt < 8; ++nt) {
        bf16x8 bf = *reinterpret_cast<const bf16x8*>(&sW[nt * 16 + ar][kk * 32 + kg * 8]);
        acc[nt] = __builtin_amdgcn_mfma_f32_16x16x32_bf16(caf[kk], bf, acc[nt], 0, 0, 0);
      }
  }
  __syncthreads();  // all waves done reading W1^T

  // ---- transpose C-layout -> A-layout via LDS scratch (aliases sW) ----
  unsigned c1p[4][4];
  {
    float* scr = reinterpret_cast<float*>(&sW[0][0]) + wv * 2112;  // 16x132 f32 per wave
#pragma unroll
    for (int nt = 0; nt < 8; ++nt)
#pragma unroll
      for (int r = 0; r < 4; ++r)
        scr[(kg * 4 + r) * 132 + nt * 16 + ar] = acc[nt][r];
    asm volatile("s_waitcnt lgkmcnt(0)" ::: "memory");
#pragma unroll
    for (int kk = 0; kk < 4; ++kk)
#pragma unroll
      for (int jj = 0; jj < 4; ++jj) {
        float f0 = scr[ar * 132 + kk * 32 + kg * 8 + jj * 2];
        float f1 = scr[ar * 132 + kk * 32 + kg * 8 + jj * 2 + 1];
        c1p[kk][jj] = pack2(f0, f1);
      }
    asm volatile("s_waitcnt lgkmcnt(0)" ::: "memory");
  }
  __syncthreads();  // scratch reads done

  // ---- stage W2^T as bf16 ----
  for (int i = tid; i < 128 * 128; i += 256) {
    int k = i >> 7, n = i & 127;
    sW[n][k] = (unsigned short)bbits(W2[i]);
  }

  // ---- x init: lane holds rows kg*4+r of its wave's 16-row tile ----
  float xq[4];
#pragma unroll
  for (int r = 0; r < 4; ++r) xq[r] = x_init[rowW + kg * 4 + r];
  if (ar == 0) {
#pragma unroll
    for (int r = 0; r < 4; ++r) sx[wv * 16 + kg * 4 + r] = xq[r];
  }

  // ---- diffusion schedule ----
  const float db = (BETA_END - BETA_START) / 99.0f;
  float acp = 1.0f;
  for (int t = 0; t < T_STEPS; ++t) acp *= (1.0f - (BETA_START + (float)t * db));
  const float b3v = b3[0];
  __syncthreads();  // W2^T staged; enter barrier-free main loop

  for (int t = T_STEPS - 1; t >= 0; --t) {
    const float beta = BETA_START + (float)t * db;
    const float alpha = 1.0f - beta;
    const float c_pred = beta * __builtin_amdgcn_rsqf(1.0f - acp);
    const float c_x = __builtin_amdgcn_rsqf(alpha);
    const float c_n = (t > 0) ? __builtin_amdgcn_sqrtf(beta) : 0.0f;
    const float te = temb[t];

    // step i = 99 - t uses noise[i]; broadcast loads (1 segment per instr)
    const size_t noff = (size_t)(T_STEPS - 1 - t) * B_N + rowW + kg * 4;
    float er[4];
#pragma unroll
    for (int r = 0; r < 4; ++r) er[r] = noise[noff + r];
    const float xv = sx[wv * 16 + ar];

#pragma unroll
    for (int nt = 0; nt < 8; ++nt) {
      float b2v = sb2[nt * 16 + ar];
      acc[nt] = (f32x4){b2v, b2v, b2v, b2v};
    }

#pragma unroll
    for (int kk = 0; kk < 4; ++kk) {
      bf16x8 af;
#pragma unroll
      for (int jj = 0; jj < 4; ++jj) {
        const unsigned cp = c1p[kk][jj];
        const uint2 wp = *reinterpret_cast<const uint2*>(&swxt[kk * 32 + kg * 8 + 2 * jj]);
        float z0 = fmaf(te, unhi(wp.x), fmaf(xv, unlo(wp.x), unlo(cp)));
        float z1 = fmaf(te, unhi(wp.y), fmaf(xv, unlo(wp.y), unhi(cp)));
        af[2 * jj]     = (__bf16)siluf(z0);
        af[2 * jj + 1] = (__bf16)siluf(z1);
      }
#pragma unroll
      for (int nt = 0; nt < 8; ++nt) {
        bf16x8 bf = *reinterpret_cast<const bf16x8*>(&sW[nt * 16 + ar][kk * 32 + kg * 8]);
        acc[nt] = __builtin_amdgcn_mfma_f32_16x16x32_bf16(af, bf, acc[nt], 0, 0, 0);
      }
    }

    // epilogue: h2 = silu(acc), pred = h2 . W3 + b3, x-update
    float p0 = 0.f, p1 = 0.f, p2 = 0.f, p3 = 0.f;
#pragma unroll
    for (int nt = 0; nt < 8; ++nt) {
      const float w3v = sw3[nt * 16 + ar];
      p0 = fmaf(siluf(acc[nt][0]), w3v, p0);
      p1 = fmaf(siluf(acc[nt][1]), w3v, p1);
      p2 = fmaf(siluf(acc[nt][2]), w3v, p2);
      p3 = fmaf(siluf(acc[nt][3]), w3v, p3);
    }
#pragma unroll
    for (int m = 1; m <= 8; m <<= 1) {
      p0 += __shfl_xor(p0, m, 64);
      p1 += __shfl_xor(p1, m, 64);
      p2 += __shfl_xor(p2, m, 64);
      p3 += __shfl_xor(p3, m, 64);
    }
    xq[0] = fmaf(c_n, er[0], (xq[0] - c_pred * (p0 + b3v)) * c_x);
    xq[1] = fmaf(c_n, er[1], (xq[1] - c_pred * (p1 + b3v)) * c_x);
    xq[2] = fmaf(c_n, er[2], (xq[2] - c_pred * (p2 + b3v)) * c_x);
    xq[3] = fmaf(c_n, er[3], (xq[3] - c_pred * (p3 + b3v)) * c_x);
    if (ar == 0) {
#pragma unroll
      for (int r = 0; r < 4; ++r) sx[wv * 16 + kg * 4 + r] = xq[r];
    }

    acp *= __builtin_amdgcn_rcpf(alpha);  // acp_{t-1} = acp_t / alpha_t
  }

  if (ar == 0) {
#pragma unroll
    for (int r = 0; r < 4; ++r) out[rowW + kg * 4 + r] = xq[r];
  }
}

extern "C" void kernel_launch(void* const* d_in, const int* in_sizes, int n_in,
                              void* d_out, int out_size, void* d_ws, size_t ws_size,
                              hipStream_t stream) {
  const float* ctx    = (const float*)d_in[0];
  const float* x_init = (const float*)d_in[1];
  const float* noise  = (const float*)d_in[2];
  const float* W1     = (const float*)d_in[3];
  const float* b1     = (const float*)d_in[4];
  const float* W2     = (const float*)d_in[5];
  const float* b2     = (const float*)d_in[6];
  const float* W3     = (const float*)d_in[7];
  const float* b3     = (const float*)d_in[8];
  const float* temb   = (const float*)d_in[9];
  float* out = (float*)d_out;

  diff_kernel<<<dim3(B_N / 64), dim3(256), 0, stream>>>(
      ctx, x_init, noise, W1, b1, W2, b2, W3, b3, temb, out);
}